// Round 1
// baseline (3571.802 us; speedup 1.0000x reference)
//
#include <hip/hip_runtime.h>
#include <math.h>

#define N_NODES 100000
#define N_EDGES 3200000
#define IN_CH 256
#define NC 20   // combined output channels (10 mu + 10 logstd)
#define OC 10

// ---------------- degree ----------------
__global__ __launch_bounds__(256) void k_init_deg(float* __restrict__ deg) {
    int i = blockIdx.x * 256 + threadIdx.x;
    if (i < N_NODES) deg[i] = 1.0f;   // self-loop
}

__global__ __launch_bounds__(256) void k_count(const int* __restrict__ col,
                                               float* __restrict__ deg) {
    int e = blockIdx.x * 256 + threadIdx.x;
    if (e < N_EDGES) atomicAdd(&deg[col[e]], 1.0f);
}

__global__ __launch_bounds__(256) void k_dinv(float* __restrict__ deg) {
    int i = blockIdx.x * 256 + threadIdx.x;
    if (i < N_NODES) deg[i] = rsqrtf(deg[i]);   // deg >= 1 guaranteed
}

// ---------------- fused skinny GEMM: h[N][20] = x @ [W_mu | W_logstd] ----------------
__global__ __launch_bounds__(256) void k_gemm(const float* __restrict__ x,
                                              const float* __restrict__ Wmu,
                                              const float* __restrict__ Wls,
                                              float* __restrict__ h) {
    __shared__ float sW[IN_CH * NC];
    int tid = threadIdx.x;
    for (int j = tid; j < IN_CH * OC; j += 256) {
        int k = j / OC, c = j - k * OC;
        sW[k * NC + c]      = Wmu[j];
        sW[k * NC + OC + c] = Wls[j];
    }
    __syncthreads();
    int node = blockIdx.x * 256 + tid;
    if (node >= N_NODES) return;

    const float4* x4 = (const float4*)(x + (size_t)node * IN_CH);
    float acc[NC];
#pragma unroll
    for (int c = 0; c < NC; c++) acc[c] = 0.0f;

#pragma unroll 4
    for (int k4 = 0; k4 < IN_CH / 4; k4++) {
        float4 xv = x4[k4];
        const float* w0 = &sW[(k4 * 4 + 0) * NC];  // wave-uniform address -> LDS broadcast
        const float* w1 = w0 + NC;
        const float* w2 = w1 + NC;
        const float* w3 = w2 + NC;
#pragma unroll
        for (int c = 0; c < NC; c++)
            acc[c] += xv.x * w0[c] + xv.y * w1[c] + xv.z * w2[c] + xv.w * w3[c];
    }

    float4* hp = (float4*)(h + (size_t)node * NC);  // 80B row, 16B aligned
    hp[0] = make_float4(acc[0],  acc[1],  acc[2],  acc[3]);
    hp[1] = make_float4(acc[4],  acc[5],  acc[6],  acc[7]);
    hp[2] = make_float4(acc[8],  acc[9],  acc[10], acc[11]);
    hp[3] = make_float4(acc[12], acc[13], acc[14], acc[15]);
    hp[4] = make_float4(acc[16], acc[17], acc[18], acc[19]);
}

// ---------------- edge scatter: out[col] += h[row] * dinv[row]*dinv[col] ----------------
__global__ __launch_bounds__(256) void k_scatter(const int* __restrict__ row,
                                                 const int* __restrict__ col,
                                                 const float* __restrict__ dinv,
                                                 const float* __restrict__ h,
                                                 float* __restrict__ out) {
    int e = blockIdx.x * 256 + threadIdx.x;
    if (e >= N_EDGES) return;
    int r = row[e], c = col[e];
    float s = dinv[r] * dinv[c];
    const float4* hp = (const float4*)(h + (size_t)r * NC);
    float4 h0 = hp[0], h1 = hp[1], h2 = hp[2], h3 = hp[3], h4 = hp[4];
    float* om = out + (size_t)c * OC;                   // mu block
    float* ol = om + (size_t)N_NODES * OC;              // logstd block
    atomicAdd(om + 0, h0.x * s);
    atomicAdd(om + 1, h0.y * s);
    atomicAdd(om + 2, h0.z * s);
    atomicAdd(om + 3, h0.w * s);
    atomicAdd(om + 4, h1.x * s);
    atomicAdd(om + 5, h1.y * s);
    atomicAdd(om + 6, h1.z * s);
    atomicAdd(om + 7, h1.w * s);
    atomicAdd(om + 8, h2.x * s);
    atomicAdd(om + 9, h2.y * s);
    atomicAdd(ol + 0, h2.z * s);
    atomicAdd(ol + 1, h2.w * s);
    atomicAdd(ol + 2, h3.x * s);
    atomicAdd(ol + 3, h3.y * s);
    atomicAdd(ol + 4, h3.z * s);
    atomicAdd(ol + 5, h3.w * s);
    atomicAdd(ol + 6, h4.x * s);
    atomicAdd(ol + 7, h4.y * s);
    atomicAdd(ol + 8, h4.z * s);
    atomicAdd(ol + 9, h4.w * s);
}

// ---------------- epilogue: self-loop + bias ----------------
__global__ __launch_bounds__(256) void k_final(const float* __restrict__ h,
                                               const float* __restrict__ dinv,
                                               const float* __restrict__ bmu,
                                               const float* __restrict__ bls,
                                               float* __restrict__ out) {
    int i = blockIdx.x * 256 + threadIdx.x;
    if (i >= N_NODES * OC) return;
    int node = i / OC, c = i - node * OC;
    float d = dinv[node];
    float d2 = d * d;
    out[i]                 += h[node * NC + c]      * d2 + bmu[c];
    out[N_NODES * OC + i]  += h[node * NC + OC + c] * d2 + bls[c];
}

extern "C" void kernel_launch(void* const* d_in, const int* in_sizes, int n_in,
                              void* d_out, int out_size, void* d_ws, size_t ws_size,
                              hipStream_t stream) {
    const float* x   = (const float*)d_in[0];
    const int*   ei  = (const int*)d_in[1];
    const float* Wmu = (const float*)d_in[2];
    const float* bmu = (const float*)d_in[3];
    const float* Wls = (const float*)d_in[4];
    const float* bls = (const float*)d_in[5];
    float* out = (float*)d_out;

    // ws layout: deg/dinv [N] f32 at 0; h [N][20] f32 at 1 MiB
    float* deg = (float*)d_ws;
    float* h   = (float*)((char*)d_ws + (1 << 20));

    const int* row = ei;            // edge_index[0]
    const int* col = ei + N_EDGES;  // edge_index[1]

    hipMemsetAsync(d_out, 0, (size_t)out_size * sizeof(float), stream);
    k_init_deg<<<(N_NODES + 255) / 256, 256, 0, stream>>>(deg);
    k_count<<<(N_EDGES + 255) / 256, 256, 0, stream>>>(col, deg);
    k_dinv<<<(N_NODES + 255) / 256, 256, 0, stream>>>(deg);
    k_gemm<<<(N_NODES + 255) / 256, 256, 0, stream>>>(x, Wmu, Wls, h);
    k_scatter<<<(N_EDGES + 255) / 256, 256, 0, stream>>>(row, col, deg, h, out);
    k_final<<<(N_NODES * OC + 255) / 256, 256, 0, stream>>>(h, deg, bmu, bls, out);
}

// Round 2
// 655.805 us; speedup vs baseline: 5.4464x; 5.4464x over previous
//
#include <hip/hip_runtime.h>
#include <math.h>

#define N_NODES 100000
#define N_EDGES 3200000
#define IN_CH 256
#define NC 20   // combined output channels (10 mu + 10 logstd)
#define OC 10
#define NB 391  // ceil(N_NODES/256)

// ======================= CSR build =======================

__global__ __launch_bounds__(256) void k_hist(const int* __restrict__ col,
                                              int* __restrict__ cnt) {
    int e = blockIdx.x * 256 + threadIdx.x;
    if (e < N_EDGES) atomicAdd(&cnt[col[e]], 1);
}

// per-block exclusive scan of cnt -> offs, block sums -> bsum
__global__ __launch_bounds__(256) void k_scan_block(const int* __restrict__ cnt,
                                                    int* __restrict__ offs,
                                                    int* __restrict__ bsum) {
    __shared__ int s[256];
    int t = threadIdx.x, b = blockIdx.x;
    int i = b * 256 + t;
    int v = (i < N_NODES) ? cnt[i] : 0;
    s[t] = v;
    __syncthreads();
    for (int off = 1; off < 256; off <<= 1) {
        int tv = (t >= off) ? s[t - off] : 0;
        __syncthreads();
        s[t] += tv;
        __syncthreads();
    }
    offs[i] = s[t] - v;           // local exclusive
    if (t == 255) bsum[b] = s[t]; // block total
}

// scan the 391 block sums (single block of 512)
__global__ __launch_bounds__(512) void k_scan_tops(const int* __restrict__ bsum,
                                                   int* __restrict__ tops) {
    __shared__ int s[512];
    int t = threadIdx.x;
    int v = (t < NB) ? bsum[t] : 0;
    s[t] = v;
    __syncthreads();
    for (int off = 1; off < 512; off <<= 1) {
        int tv = (t >= off) ? s[t - off] : 0;
        __syncthreads();
        s[t] += tv;
        __syncthreads();
    }
    tops[t] = s[t] - v;           // exclusive
}

// offs += tops[block]; pos = offs; dinv = rsqrt(cnt+1)
__global__ __launch_bounds__(256) void k_scan_add(int* __restrict__ offs,
                                                  const int* __restrict__ tops,
                                                  int* __restrict__ pos,
                                                  const int* __restrict__ cnt,
                                                  float* __restrict__ dinv) {
    int b = blockIdx.x, t = threadIdx.x;
    int i = b * 256 + t;
    int o = offs[i] + tops[b];
    offs[i] = o;
    pos[i] = o;
    if (i < N_NODES) dinv[i] = rsqrtf((float)(cnt[i] + 1)); // +1 self loop
}

__global__ __launch_bounds__(256) void k_fill(const int* __restrict__ row,
                                              const int* __restrict__ col,
                                              int* __restrict__ pos,
                                              int* __restrict__ csr_src) {
    int e = blockIdx.x * 256 + threadIdx.x;
    if (e >= N_EDGES) return;
    int c = col[e];
    int slot = atomicAdd(&pos[c], 1);
    csr_src[slot] = row[e];
}

// ======================= fused skinny GEMM: h[N][20] = x @ [W_mu | W_logstd] =======================
__global__ __launch_bounds__(256) void k_gemm(const float* __restrict__ x,
                                              const float* __restrict__ Wmu,
                                              const float* __restrict__ Wls,
                                              float* __restrict__ h) {
    __shared__ float sW[IN_CH * NC];
    int tid = threadIdx.x;
    for (int j = tid; j < IN_CH * OC; j += 256) {
        int k = j / OC, c = j - k * OC;
        sW[k * NC + c]      = Wmu[j];
        sW[k * NC + OC + c] = Wls[j];
    }
    __syncthreads();
    int node = blockIdx.x * 256 + tid;
    if (node >= N_NODES) return;

    const float4* x4 = (const float4*)(x + (size_t)node * IN_CH);
    float acc[NC];
#pragma unroll
    for (int c = 0; c < NC; c++) acc[c] = 0.0f;

#pragma unroll 4
    for (int k4 = 0; k4 < IN_CH / 4; k4++) {
        float4 xv = x4[k4];
        const float* w0 = &sW[(k4 * 4 + 0) * NC];
        const float* w1 = w0 + NC;
        const float* w2 = w1 + NC;
        const float* w3 = w2 + NC;
#pragma unroll
        for (int c = 0; c < NC; c++)
            acc[c] += xv.x * w0[c] + xv.y * w1[c] + xv.z * w2[c] + xv.w * w3[c];
    }

    float4* hp = (float4*)(h + (size_t)node * NC);
    hp[0] = make_float4(acc[0],  acc[1],  acc[2],  acc[3]);
    hp[1] = make_float4(acc[4],  acc[5],  acc[6],  acc[7]);
    hp[2] = make_float4(acc[8],  acc[9],  acc[10], acc[11]);
    hp[3] = make_float4(acc[12], acc[13], acc[14], acc[15]);
    hp[4] = make_float4(acc[16], acc[17], acc[18], acc[19]);
}

// ======================= gather reduce =======================
// thread = (node, channel-group g of 4); out written exactly once (no memset needed)
__global__ __launch_bounds__(256) void k_gather(const int* __restrict__ offs,
                                                const int* __restrict__ cnt,
                                                const int* __restrict__ csr_src,
                                                const float* __restrict__ dinv,
                                                const float* __restrict__ h,
                                                const float* __restrict__ bmu,
                                                const float* __restrict__ bls,
                                                float* __restrict__ out) {
    int gid = blockIdx.x * 256 + threadIdx.x;
    int node = gid / 5;
    int g = gid - node * 5;
    if (node >= N_NODES) return;
    int start = offs[node], n = cnt[node];
    const int* src = csr_src + start;

    float a0 = 0.f, a1 = 0.f, a2 = 0.f, a3 = 0.f;
    int j = 0;
    for (; j + 1 < n; j += 2) {   // 2-way unroll for load ILP
        int r0 = src[j], r1 = src[j + 1];
        float s0 = dinv[r0], s1 = dinv[r1];
        float4 v0 = *(const float4*)(h + (size_t)r0 * NC + g * 4);
        float4 v1 = *(const float4*)(h + (size_t)r1 * NC + g * 4);
        a0 += s0 * v0.x + s1 * v1.x;
        a1 += s0 * v0.y + s1 * v1.y;
        a2 += s0 * v0.z + s1 * v1.z;
        a3 += s0 * v0.w + s1 * v1.w;
    }
    if (j < n) {
        int r0 = src[j];
        float s0 = dinv[r0];
        float4 v0 = *(const float4*)(h + (size_t)r0 * NC + g * 4);
        a0 += s0 * v0.x; a1 += s0 * v0.y; a2 += s0 * v0.z; a3 += s0 * v0.w;
    }
    // self loop
    float dn = dinv[node];
    float4 hs = *(const float4*)(h + (size_t)node * NC + g * 4);
    a0 += dn * hs.x; a1 += dn * hs.y; a2 += dn * hs.z; a3 += dn * hs.w;

    float acc[4] = {a0, a1, a2, a3};
#pragma unroll
    for (int k = 0; k < 4; k++) {
        int cc = g * 4 + k;
        float b = (cc < OC) ? bmu[cc] : bls[cc - OC];
        float val = dn * acc[k] + b;
        size_t idx = (cc < OC) ? ((size_t)node * OC + cc)
                               : ((size_t)N_NODES * OC + (size_t)node * OC + (cc - OC));
        out[idx] = val;
    }
}

// ======================= fallback (round-1 atomic path, if ws too small) =======================
__global__ __launch_bounds__(256) void k_init_deg(float* __restrict__ deg) {
    int i = blockIdx.x * 256 + threadIdx.x;
    if (i < N_NODES) deg[i] = 1.0f;
}
__global__ __launch_bounds__(256) void k_count(const int* __restrict__ col, float* __restrict__ deg) {
    int e = blockIdx.x * 256 + threadIdx.x;
    if (e < N_EDGES) atomicAdd(&deg[col[e]], 1.0f);
}
__global__ __launch_bounds__(256) void k_dinv(float* __restrict__ deg) {
    int i = blockIdx.x * 256 + threadIdx.x;
    if (i < N_NODES) deg[i] = rsqrtf(deg[i]);
}
__global__ __launch_bounds__(256) void k_scatter(const int* __restrict__ row, const int* __restrict__ col,
                                                 const float* __restrict__ dinv, const float* __restrict__ h,
                                                 float* __restrict__ out) {
    int e = blockIdx.x * 256 + threadIdx.x;
    if (e >= N_EDGES) return;
    int r = row[e], c = col[e];
    float s = dinv[r] * dinv[c];
    const float4* hp = (const float4*)(h + (size_t)r * NC);
    float4 h0 = hp[0], h1 = hp[1], h2 = hp[2], h3 = hp[3], h4 = hp[4];
    float* om = out + (size_t)c * OC;
    float* ol = om + (size_t)N_NODES * OC;
    atomicAdd(om + 0, h0.x * s); atomicAdd(om + 1, h0.y * s); atomicAdd(om + 2, h0.z * s);
    atomicAdd(om + 3, h0.w * s); atomicAdd(om + 4, h1.x * s); atomicAdd(om + 5, h1.y * s);
    atomicAdd(om + 6, h1.z * s); atomicAdd(om + 7, h1.w * s); atomicAdd(om + 8, h2.x * s);
    atomicAdd(om + 9, h2.y * s);
    atomicAdd(ol + 0, h2.z * s); atomicAdd(ol + 1, h2.w * s); atomicAdd(ol + 2, h3.x * s);
    atomicAdd(ol + 3, h3.y * s); atomicAdd(ol + 4, h3.z * s); atomicAdd(ol + 5, h3.w * s);
    atomicAdd(ol + 6, h4.x * s); atomicAdd(ol + 7, h4.y * s); atomicAdd(ol + 8, h4.z * s);
    atomicAdd(ol + 9, h4.w * s);
}
__global__ __launch_bounds__(256) void k_final(const float* __restrict__ h, const float* __restrict__ dinv,
                                               const float* __restrict__ bmu, const float* __restrict__ bls,
                                               float* __restrict__ out) {
    int i = blockIdx.x * 256 + threadIdx.x;
    if (i >= N_NODES * OC) return;
    int node = i / OC, c = i - node * OC;
    float d = dinv[node];
    float d2 = d * d;
    out[i]                += h[node * NC + c]      * d2 + bmu[c];
    out[N_NODES * OC + i] += h[node * NC + OC + c] * d2 + bls[c];
}

extern "C" void kernel_launch(void* const* d_in, const int* in_sizes, int n_in,
                              void* d_out, int out_size, void* d_ws, size_t ws_size,
                              hipStream_t stream) {
    const float* x   = (const float*)d_in[0];
    const int*   ei  = (const int*)d_in[1];
    const float* Wmu = (const float*)d_in[2];
    const float* bmu = (const float*)d_in[3];
    const float* Wls = (const float*)d_in[4];
    const float* bls = (const float*)d_in[5];
    float* out = (float*)d_out;

    const int* row = ei;            // edge_index[0] (sources)
    const int* col = ei + N_EDGES;  // edge_index[1] (targets)

    // ws layout (CSR path):
    //   cnt  int[100096]   @ 0        (512 KiB slot)
    //   offs int[100096]   @ 512K
    //   pos  int[100096]   @ 1M
    //   dinv f32[100000]   @ 1.5M
    //   bsum int[512]      @ 2M
    //   tops int[512]      @ 2M+4K
    //   h    f32[N*20]     @ 4M       (8 MB)
    //   csr  int[E]        @ 12M      (12.8 MB)
    const size_t REQ = (12 << 20) + (size_t)N_EDGES * 4;

    if (ws_size >= REQ) {
        char* w = (char*)d_ws;
        int*   cnt  = (int*)(w);
        int*   offs = (int*)(w + (512 << 10));
        int*   pos  = (int*)(w + (1 << 20));
        float* dinv = (float*)(w + (3 << 19));       // 1.5 MiB
        int*   bsum = (int*)(w + (2 << 20));
        int*   tops = (int*)(w + (2 << 20) + 4096);
        float* h    = (float*)(w + (4 << 20));
        int*   csr  = (int*)(w + (12 << 20));

        hipMemsetAsync(cnt, 0, NB * 256 * sizeof(int), stream);
        k_hist<<<(N_EDGES + 255) / 256, 256, 0, stream>>>(col, cnt);
        k_scan_block<<<NB, 256, 0, stream>>>(cnt, offs, bsum);
        k_scan_tops<<<1, 512, 0, stream>>>(bsum, tops);
        k_scan_add<<<NB, 256, 0, stream>>>(offs, tops, pos, cnt, dinv);
        k_fill<<<(N_EDGES + 255) / 256, 256, 0, stream>>>(row, col, pos, csr);
        k_gemm<<<(N_NODES + 255) / 256, 256, 0, stream>>>(x, Wmu, Wls, h);
        k_gather<<<(N_NODES * 5 + 255) / 256, 256, 0, stream>>>(offs, cnt, csr, dinv, h, bmu, bls, out);
    } else {
        // fallback: atomic scatter (round-1 path)
        float* deg = (float*)d_ws;
        float* h   = (float*)((char*)d_ws + (1 << 20));
        hipMemsetAsync(d_out, 0, (size_t)out_size * sizeof(float), stream);
        k_init_deg<<<(N_NODES + 255) / 256, 256, 0, stream>>>(deg);
        k_count<<<(N_EDGES + 255) / 256, 256, 0, stream>>>(col, deg);
        k_dinv<<<(N_NODES + 255) / 256, 256, 0, stream>>>(deg);
        k_gemm<<<(N_NODES + 255) / 256, 256, 0, stream>>>(x, Wmu, Wls, h);
        k_scatter<<<(N_EDGES + 255) / 256, 256, 0, stream>>>(row, col, deg, h, out);
        k_final<<<(N_NODES * OC + 255) / 256, 256, 0, stream>>>(h, deg, bmu, bls, out);
    }
}